// Round 10
// baseline (274.921 us; speedup 1.0000x reference)
//
#include <hip/hip_runtime.h>

// MHA: B=8, N=1024, D=768, H=12, HD=64. FLOAT32 in/out, bf16 MFMA internally.
// Round 10: software-pipelined attn (S(jt+1) MFMA burst fills P(jt) ds_read
// latency; loads for jt+1 in flight under iteration jt); 2-wave blocks for
// qkv/out_proj (no LDS -> ~24 waves/CU for latency hiding).

typedef __attribute__((ext_vector_type(8))) short short8;   // 8 x bf16 bits
typedef __attribute__((ext_vector_type(4))) float floatx4;  // MFMA acc

#define MFMA16(a, b, c) __builtin_amdgcn_mfma_f32_16x16x32_bf16((a), (b), (c), 0, 0, 0)

#if __has_builtin(__builtin_amdgcn_exp2f)
#define EXP2(x) __builtin_amdgcn_exp2f(x)
#else
#define EXP2(x) __expf(0.6931471805599453f * (x))
#endif
#if __has_builtin(__builtin_amdgcn_rcpf)
#define RCP(x) __builtin_amdgcn_rcpf(x)
#else
#define RCP(x) (1.0f / (x))
#endif

__device__ __forceinline__ unsigned short f2bf(float f) {
    union { float f; unsigned int i; } c;
    c.f = f;
    unsigned int i = c.i;
    return (unsigned short)((i + 0x7fffu + ((i >> 16) & 1u)) >> 16);  // RNE
}
__device__ __forceinline__ unsigned short f2bf_trunc(float f) {
    union { float f; unsigned int i; } c;
    c.f = f;
    return (unsigned short)(c.i >> 16);  // folds into ds_write_b16_d16_hi
}

// ---------------------------------------------------------------------------
// Phase 0: Wt[h][e][k] = W[h][k][e] (bf16), Wo_bf = bf16(Wo).
// ---------------------------------------------------------------------------
__global__ __launch_bounds__(256) void prep_weights(
    const float* __restrict__ Wq, const float* __restrict__ Wk,
    const float* __restrict__ Wv, const float* __restrict__ Wo,
    unsigned short* __restrict__ Wqt, unsigned short* __restrict__ Wkt,
    unsigned short* __restrict__ Wvt, unsigned short* __restrict__ Wob)
{
    int tid = blockIdx.x * 256 + threadIdx.x;  // 0..147455
    if (tid < 49152) {                          // 12 heads * 4096 only
        int h = tid >> 12, r = tid & 4095;
        int e = r >> 6, k = r & 63;
        int src = h * 4096 + k * 64 + e, dst = h * 4096 + e * 64 + k;
        Wqt[dst] = f2bf(Wq[src]);
        Wkt[dst] = f2bf(Wk[src]);
        Wvt[dst] = f2bf(Wv[src]);
    }
    for (int i = tid; i < 589824; i += 147456) Wob[i] = f2bf(Wo[i]);
}

// ---------------------------------------------------------------------------
// Phase 1: Q/K (row-major, Q pre-scaled by 768^-0.5*log2e) and Vt per head.
// grid (32, 96), block 128 (2 waves x 16 rows): 3072 blocks, no LDS ->
// ~24 waves/CU for latency hiding.
// ---------------------------------------------------------------------------
__global__ __launch_bounds__(128) void qkv_proj(
    const float* __restrict__ x,
    const unsigned short* __restrict__ Wqt, const unsigned short* __restrict__ Wkt,
    const unsigned short* __restrict__ Wvt,
    const float* __restrict__ bq, const float* __restrict__ bk,
    const float* __restrict__ bv,
    unsigned short* __restrict__ Q, unsigned short* __restrict__ K,
    unsigned short* __restrict__ Vt)
{
    const int bh = blockIdx.y;
    const int b = bh / 12, h = bh % 12;
    const int wave = threadIdx.x >> 6, lane = threadIdx.x & 63;
    const int lrow = lane & 15, quad = lane >> 4;
    const int row0 = blockIdx.x * 32 + wave * 16;
    const float scale = 0.052058776672f;  // 768^-0.5 * log2(e): p = 2^s

    const float* xrow = x + ((size_t)(b * 1024 + row0 + lrow)) * 768 + h * 64;
    float4 xv0 = *(const float4*)(xrow + quad * 8);
    float4 xv1 = *(const float4*)(xrow + quad * 8 + 4);
    float4 xv2 = *(const float4*)(xrow + 32 + quad * 8);
    float4 xv3 = *(const float4*)(xrow + 32 + quad * 8 + 4);
    short8 a0, a1;
    a0[0] = (short)f2bf(xv0.x); a0[1] = (short)f2bf(xv0.y);
    a0[2] = (short)f2bf(xv0.z); a0[3] = (short)f2bf(xv0.w);
    a0[4] = (short)f2bf(xv1.x); a0[5] = (short)f2bf(xv1.y);
    a0[6] = (short)f2bf(xv1.z); a0[7] = (short)f2bf(xv1.w);
    a1[0] = (short)f2bf(xv2.x); a1[1] = (short)f2bf(xv2.y);
    a1[2] = (short)f2bf(xv2.z); a1[3] = (short)f2bf(xv2.w);
    a1[4] = (short)f2bf(xv3.x); a1[5] = (short)f2bf(xv3.y);
    a1[6] = (short)f2bf(xv3.z); a1[7] = (short)f2bf(xv3.w);

    const floatx4 zero = { 0.f, 0.f, 0.f, 0.f };

    // ---- Q and K ----
    const unsigned short* Wm[2] = { Wqt + h * 4096, Wkt + h * 4096 };
    const float* bm[2] = { bq + h * 64, bk + h * 64 };
    unsigned short* Om[2] = { Q, K };
    #pragma unroll
    for (int m = 0; m < 2; ++m) {
        const unsigned short* W = Wm[m];
        unsigned short* O = Om[m] + ((size_t)bh * 1024 + row0) * 64;
        #pragma unroll
        for (int t = 0; t < 4; ++t) {
            short8 b0 = *(const short8*)(W + (t * 16 + lrow) * 64 + quad * 8);
            short8 b1 = *(const short8*)(W + (t * 16 + lrow) * 64 + 32 + quad * 8);
            floatx4 acc = zero;
            acc = MFMA16(a0, b0, acc);
            acc = MFMA16(a1, b1, acc);
            float bias = bm[m][t * 16 + lrow];
            #pragma unroll
            for (int r = 0; r < 4; ++r) {
                float v = acc[r] + bias;
                if (m == 0) v *= scale;  // fold score scale (incl log2e) into Q
                O[(quad * 4 + r) * 64 + t * 16 + lrow] = f2bf(v);
            }
        }
    }

    // ---- V transposed: D[e][seq] = sum_k Wv[k][e] * x[seq][k] ----
    {
        const unsigned short* W = Wvt + h * 4096;
        const float* bvh = bv + h * 64;
        unsigned short* O = Vt + (size_t)bh * 64 * 1024;
        #pragma unroll
        for (int t = 0; t < 4; ++t) {
            short8 wa0 = *(const short8*)(W + (t * 16 + lrow) * 64 + quad * 8);
            short8 wa1 = *(const short8*)(W + (t * 16 + lrow) * 64 + 32 + quad * 8);
            floatx4 acc = zero;
            acc = MFMA16(wa0, a0, acc);  // B-frag = x fragment
            acc = MFMA16(wa1, a1, acc);
            #pragma unroll
            for (int r = 0; r < 4; ++r) {
                int e = t * 16 + quad * 4 + r;
                O[(size_t)e * 1024 + row0 + lrow] = f2bf(acc[r] + bvh[e]);
            }
        }
    }
}

// ---------------------------------------------------------------------------
// Phase 2: flash attention. grid (16, 96), block 256, wave = 32 q-rows,
// split-KV x2 (wave pairs). SOFTWARE PIPELINED: the S(jt+1) MFMA burst sits
// between the P(jt) ds_read and the PV(jt) MFMAs, so the LDS round-trip
// latency is covered by matrix work; K(jt+1)/V(jt) loads are issued at the
// iteration top and consumed ~400 cycles later.
// ---------------------------------------------------------------------------
__global__ __launch_bounds__(256) void attn_kernel(
    const unsigned short* __restrict__ Q, const unsigned short* __restrict__ K,
    const unsigned short* __restrict__ Vt, unsigned short* __restrict__ AO)
{
    // P tiles (4 waves x 2 mm x 16 x 72 u16 = 18432 B); reused as f32
    // combine buffers (16 KB + 4 KB) after the KV loop. 20480 B total.
    __shared__ __align__(16) float smem[5120];

    const int id = blockIdx.x + 16 * blockIdx.y;         // flat, x-fastest
    const int bh = (id & 7) * 12 + ((id % 96) >> 3);     // XCD-clustered bh
    const int qb = id / 96;                              // 0..15
    const int b = bh / 12, h = bh % 12;
    const int wave = threadIdx.x >> 6, lane = threadIdx.x & 63;
    const int lrow = lane & 15, quad = lane >> 4;
    const int mg = wave >> 1, half = wave & 1;
    const int qrow0 = qb * 64 + mg * 32;
    const int kv0 = half * 512;

    unsigned short* Pw = (unsigned short*)smem + wave * (2 * 16 * 72);

    const unsigned short* Qb = Q + (size_t)bh * 65536;
    const unsigned short* Kb = K + (size_t)bh * 65536;
    const unsigned short* Vb = Vt + (size_t)bh * 65536;

    short8 aq[2][2];
    #pragma unroll
    for (int mm = 0; mm < 2; ++mm) {
        const unsigned short* qr = Qb + (size_t)(qrow0 + mm * 16 + lrow) * 64;
        aq[mm][0] = *(const short8*)(qr + quad * 8);
        aq[mm][1] = *(const short8*)(qr + 32 + quad * 8);
    }

    const floatx4 zero = { 0.f, 0.f, 0.f, 0.f };
    float part[2][4];
    floatx4 Oacc[2][4];
    #pragma unroll
    for (int mm = 0; mm < 2; ++mm) {
        #pragma unroll
        for (int r = 0; r < 4; ++r) part[mm][r] = 0.f;
        #pragma unroll
        for (int t = 0; t < 4; ++t) Oacc[mm][t] = zero;
    }

    short8 kf[4][2];

    // ---- prologue: S(0) -> exp -> P(0) in LDS ----
    #pragma unroll
    for (int g = 0; g < 4; ++g) {
        const unsigned short* kr = Kb + (size_t)(kv0 + g * 16 + lrow) * 64;
        kf[g][0] = *(const short8*)(kr + quad * 8);
        kf[g][1] = *(const short8*)(kr + 32 + quad * 8);
    }
    #pragma unroll
    for (int mm = 0; mm < 2; ++mm)
        #pragma unroll
        for (int g = 0; g < 4; ++g) {
            floatx4 s = zero;
            s = MFMA16(aq[mm][0], kf[g][0], s);
            s = MFMA16(aq[mm][1], kf[g][1], s);
            #pragma unroll
            for (int r = 0; r < 4; ++r) {
                float p = EXP2(s[r]);
                part[mm][r] += p;
                Pw[(mm * 16 + quad * 4 + r) * 72 + g * 16 + lrow] = f2bf_trunc(p);
            }
        }

    // ---- pipelined KV loop ----
    for (int jt = 0; jt < 8; ++jt) {
        const int j0 = kv0 + jt * 64;
        const int jn = kv0 + ((jt + 1) & 7) * 64;  // wraps on last iter

        // issue K(jt+1) loads (consumed by the S burst below)
        #pragma unroll
        for (int g = 0; g < 4; ++g) {
            const unsigned short* kr = Kb + (size_t)(jn + g * 16 + lrow) * 64;
            kf[g][0] = *(const short8*)(kr + quad * 8);
            kf[g][1] = *(const short8*)(kr + 32 + quad * 8);
        }
        // issue V(jt) loads (consumed by PV at the bottom)
        short8 vf[4][2];
        #pragma unroll
        for (int t = 0; t < 4; ++t) {
            const unsigned short* vr = Vb + (size_t)(t * 16 + lrow) * 1024 + j0;
            vf[t][0] = *(const short8*)(vr + quad * 8);
            vf[t][1] = *(const short8*)(vr + 32 + quad * 8);
        }
        // issue P(jt) read (DS ordered after last iter's writes)
        short8 aP[2][2];
        #pragma unroll
        for (int mm = 0; mm < 2; ++mm) {
            aP[mm][0] = *(const short8*)(Pw + (mm * 16 + lrow) * 72 + quad * 8);
            aP[mm][1] = *(const short8*)(Pw + (mm * 16 + lrow) * 72 + 32 + quad * 8);
        }

        // S(jt+1) burst + exp + P(jt+1) writes — fills the ds_read latency.
        // Guarded: jt==7 must not re-accumulate tile 0 into part.
        if (jt < 7) {
            floatx4 S[2][4];
            #pragma unroll
            for (int mm = 0; mm < 2; ++mm)
                #pragma unroll
                for (int g = 0; g < 4; ++g) {
                    floatx4 s = zero;
                    s = MFMA16(aq[mm][0], kf[g][0], s);
                    s = MFMA16(aq[mm][1], kf[g][1], s);
                    S[mm][g] = s;
                }
            #pragma unroll
            for (int mm = 0; mm < 2; ++mm)
                #pragma unroll
                for (int g = 0; g < 4; ++g)
                    #pragma unroll
                    for (int r = 0; r < 4; ++r) {
                        float p = EXP2(S[mm][g][r]);
                        part[mm][r] += p;
                        Pw[(mm * 16 + quad * 4 + r) * 72 + g * 16 + lrow]
                            = f2bf_trunc(p);
                    }
        }

        // PV(jt)
        #pragma unroll
        for (int t = 0; t < 4; ++t)
            #pragma unroll
            for (int mm = 0; mm < 2; ++mm) {
                Oacc[mm][t] = MFMA16(aP[mm][0], vf[t][0], Oacc[mm][t]);
                Oacc[mm][t] = MFMA16(aP[mm][1], vf[t][1], Oacc[mm][t]);
            }
    }

    // ---- combine KV halves (exact: O and sum(p) add linearly) ----
    __syncthreads();
    float* obuf = smem;          // [2 mg][32 i][64 lane] = 16 KB
    float* pbuf = smem + 4096;   // [2 mg][8 i][64 lane]  =  4 KB
    if (half == 1) {
        #pragma unroll
        for (int mm = 0; mm < 2; ++mm) {
            #pragma unroll
            for (int t = 0; t < 4; ++t)
                #pragma unroll
                for (int r = 0; r < 4; ++r)
                    obuf[(mg * 32 + mm * 16 + t * 4 + r) * 64 + lane] = Oacc[mm][t][r];
            #pragma unroll
            for (int r = 0; r < 4; ++r)
                pbuf[(mg * 8 + mm * 4 + r) * 64 + lane] = part[mm][r];
        }
    }
    __syncthreads();
    if (half == 0) {
        #pragma unroll
        for (int mm = 0; mm < 2; ++mm) {
            float inv[4];
            #pragma unroll
            for (int r = 0; r < 4; ++r) {
                float ts = part[mm][r] + pbuf[(mg * 8 + mm * 4 + r) * 64 + lane];
                ts += __shfl_xor(ts, 1);
                ts += __shfl_xor(ts, 2);
                ts += __shfl_xor(ts, 4);
                ts += __shfl_xor(ts, 8);
                inv[r] = RCP(ts);
            }
            #pragma unroll
            for (int t = 0; t < 4; ++t)
                #pragma unroll
                for (int r = 0; r < 4; ++r) {
                    float val = (Oacc[mm][t][r]
                        + obuf[(mg * 32 + mm * 16 + t * 4 + r) * 64 + lane]) * inv[r];
                    size_t idx = ((size_t)(b * 1024 + qrow0 + mm * 16 + quad * 4 + r)) * 768
                               + h * 64 + t * 16 + lrow;
                    AO[idx] = f2bf(val);
                }
        }
    }
}

// ---------------------------------------------------------------------------
// Phase 3: Y = AO @ Wo^T + bo. grid (256, 12), block 128 (2 waves).
// Wave = 32 rows x 32 cols; 3072 blocks, no LDS -> ~24 waves/CU.
// XCD pinning: flat id x-fastest -> XCD = rowgroup % 8; a rowgroup's 12
// c-blocks share ids mod 256 (== mod 8) -> same XCD, AO row-tile L2-resident.
// ---------------------------------------------------------------------------
__global__ __launch_bounds__(128) void out_proj(
    const unsigned short* __restrict__ AO, const unsigned short* __restrict__ Wob,
    const float* __restrict__ bo, float* __restrict__ Y)
{
    const int wave = threadIdx.x >> 6, lane = threadIdx.x & 63;
    const int lrow = lane & 15, quad = lane >> 4;
    const int row0 = blockIdx.x * 32;
    const int c0 = blockIdx.y * 64 + wave * 32;

    const unsigned short* Ar[2];
    Ar[0] = AO + (size_t)(row0 + lrow) * 768 + quad * 8;
    Ar[1] = AO + (size_t)(row0 + 16 + lrow) * 768 + quad * 8;
    const unsigned short* Br[2];
    Br[0] = Wob + (size_t)(c0 + lrow) * 768 + quad * 8;
    Br[1] = Wob + (size_t)(c0 + 16 + lrow) * 768 + quad * 8;

    const floatx4 zero = { 0.f, 0.f, 0.f, 0.f };
    floatx4 acc[2][2];
    #pragma unroll
    for (int m = 0; m < 2; ++m)
        #pragma unroll
        for (int t = 0; t < 2; ++t) acc[m][t] = zero;

    short8 a[2], bb[2];
    a[0] = *(const short8*)(Ar[0]);
    a[1] = *(const short8*)(Ar[1]);
    bb[0] = *(const short8*)(Br[0]);
    bb[1] = *(const short8*)(Br[1]);

    for (int k0 = 0; k0 < 768; k0 += 32) {
        const int kn = (k0 + 32 < 768) ? k0 + 32 : 0;  // harmless wrap
        short8 an[2], bn[2];
        an[0] = *(const short8*)(Ar[0] + kn);
        an[1] = *(const short8*)(Ar[1] + kn);
        bn[0] = *(const short8*)(Br[0] + kn);
        bn[1] = *(const short8*)(Br[1] + kn);

        #pragma unroll
        for (int t = 0; t < 2; ++t)
            #pragma unroll
            for (int m = 0; m < 2; ++m)
                acc[m][t] = MFMA16(a[m], bb[t], acc[m][t]);

        a[0] = an[0]; a[1] = an[1];
        bb[0] = bn[0]; bb[1] = bn[1];
    }
    #pragma unroll
    for (int t = 0; t < 2; ++t) {
        float bias = bo[c0 + t * 16 + lrow];
        #pragma unroll
        for (int m = 0; m < 2; ++m)
            #pragma unroll
            for (int r = 0; r < 4; ++r) {
                Y[(size_t)(row0 + m * 16 + quad * 4 + r) * 768 + c0 + t * 16 + lrow]
                    = acc[m][t][r] + bias;
            }
    }
}

extern "C" void kernel_launch(void* const* d_in, const int* in_sizes, int n_in,
                              void* d_out, int out_size, void* d_ws, size_t ws_size,
                              hipStream_t stream)
{
    const float* x  = (const float*)d_in[0];
    const float* Wq = (const float*)d_in[1];
    const float* Wk = (const float*)d_in[2];
    const float* Wv = (const float*)d_in[3];
    const float* bq = (const float*)d_in[4];
    const float* bk = (const float*)d_in[5];
    const float* bv = (const float*)d_in[6];
    const float* Wo = (const float*)d_in[7];
    const float* bo = (const float*)d_in[8];

    // ws layout (bf16 elements)
    unsigned short* Q   = (unsigned short*)d_ws;        // 6291456
    unsigned short* K   = Q + 6291456;                  // 6291456
    unsigned short* Vt  = K + 6291456;                  // 6291456 (transposed)
    unsigned short* AO  = Vt + 6291456;                 // 6291456
    unsigned short* Wqt = AO + 6291456;                 // 49152
    unsigned short* Wkt = Wqt + 49152;                  // 49152
    unsigned short* Wvt = Wkt + 49152;                  // 49152
    unsigned short* Wob = Wvt + 49152;                  // 589824
    float* Y = (float*)d_out;

    prep_weights<<<dim3(576), 256, 0, stream>>>(Wq, Wk, Wv, Wo, Wqt, Wkt, Wvt, Wob);
    qkv_proj<<<dim3(32, 96), 128, 0, stream>>>(x, Wqt, Wkt, Wvt, bq, bk, bv, Q, K, Vt);
    attn_kernel<<<dim3(16, 96), 256, 0, stream>>>(Q, K, Vt, AO);
    out_proj<<<dim3(256, 12), 128, 0, stream>>>(AO, Wob, bo, Y);
}

// Round 11
// 256.120 us; speedup vs baseline: 1.0734x; 1.0734x over previous
//
#include <hip/hip_runtime.h>

// MHA: B=8, N=1024, D=768, H=12, HD=64. FLOAT32 in/out, bf16 MFMA internally.
// Round 11: attention with REGISTER-ONLY P transform. Compute S^T (A=K, B=Q)
// with permuted K-row tiles so the S^T C-layout (col=q=lane&15, row=quad*4+r,
// kv=quad*8+r+4*tile) is bit-exactly the PV B-operand layout after an
// in-register trunc-pack. No LDS / barriers / bank conflicts in the KV loop.
// qkv_proj / out_proj reverted to the round-8 (fastest measured) versions.

typedef __attribute__((ext_vector_type(8))) short short8;   // 8 x bf16 bits
typedef __attribute__((ext_vector_type(4))) float floatx4;  // MFMA acc

#define MFMA16(a, b, c) __builtin_amdgcn_mfma_f32_16x16x32_bf16((a), (b), (c), 0, 0, 0)

#if __has_builtin(__builtin_amdgcn_exp2f)
#define EXP2(x) __builtin_amdgcn_exp2f(x)
#else
#define EXP2(x) __expf(0.6931471805599453f * (x))
#endif
#if __has_builtin(__builtin_amdgcn_rcpf)
#define RCP(x) __builtin_amdgcn_rcpf(x)
#else
#define RCP(x) (1.0f / (x))
#endif

__device__ __forceinline__ unsigned short f2bf(float f) {
    union { float f; unsigned int i; } c;
    c.f = f;
    unsigned int i = c.i;
    return (unsigned short)((i + 0x7fffu + ((i >> 16) & 1u)) >> 16);  // RNE
}
__device__ __forceinline__ unsigned short f2bf_trunc(float f) {
    union { float f; unsigned int i; } c;
    c.f = f;
    return (unsigned short)(c.i >> 16);
}

// ---------------------------------------------------------------------------
// Phase 0: Wt[h][e][k] = W[h][k][e] (bf16), Wo_bf = bf16(Wo).
// ---------------------------------------------------------------------------
__global__ __launch_bounds__(256) void prep_weights(
    const float* __restrict__ Wq, const float* __restrict__ Wk,
    const float* __restrict__ Wv, const float* __restrict__ Wo,
    unsigned short* __restrict__ Wqt, unsigned short* __restrict__ Wkt,
    unsigned short* __restrict__ Wvt, unsigned short* __restrict__ Wob)
{
    int tid = blockIdx.x * 256 + threadIdx.x;  // 0..147455
    if (tid < 49152) {                          // 12 heads * 4096 only
        int h = tid >> 12, r = tid & 4095;
        int e = r >> 6, k = r & 63;
        int src = h * 4096 + k * 64 + e, dst = h * 4096 + e * 64 + k;
        Wqt[dst] = f2bf(Wq[src]);
        Wkt[dst] = f2bf(Wk[src]);
        Wvt[dst] = f2bf(Wv[src]);
    }
    for (int i = tid; i < 589824; i += 147456) Wob[i] = f2bf(Wo[i]);
}

// ---------------------------------------------------------------------------
// Phase 1 (round-8 version): Q/K (Q pre-scaled by 768^-0.5*log2e), Vt.
// grid (16, 96), block 256 (4 waves x 16 rows). float4 x-loads.
// ---------------------------------------------------------------------------
__global__ __launch_bounds__(256) void qkv_proj(
    const float* __restrict__ x,
    const unsigned short* __restrict__ Wqt, const unsigned short* __restrict__ Wkt,
    const unsigned short* __restrict__ Wvt,
    const float* __restrict__ bq, const float* __restrict__ bk,
    const float* __restrict__ bv,
    unsigned short* __restrict__ Q, unsigned short* __restrict__ K,
    unsigned short* __restrict__ Vt)
{
    const int bh = blockIdx.y;
    const int b = bh / 12, h = bh % 12;
    const int wave = threadIdx.x >> 6, lane = threadIdx.x & 63;
    const int lrow = lane & 15, quad = lane >> 4;
    const int row0 = blockIdx.x * 64 + wave * 16;
    const float scale = 0.052058776672f;  // 768^-0.5 * log2(e): p = 2^s

    const float* xrow = x + ((size_t)(b * 1024 + row0 + lrow)) * 768 + h * 64;
    float4 xv0 = *(const float4*)(xrow + quad * 8);
    float4 xv1 = *(const float4*)(xrow + quad * 8 + 4);
    float4 xv2 = *(const float4*)(xrow + 32 + quad * 8);
    float4 xv3 = *(const float4*)(xrow + 32 + quad * 8 + 4);
    short8 a0, a1;
    a0[0] = (short)f2bf(xv0.x); a0[1] = (short)f2bf(xv0.y);
    a0[2] = (short)f2bf(xv0.z); a0[3] = (short)f2bf(xv0.w);
    a0[4] = (short)f2bf(xv1.x); a0[5] = (short)f2bf(xv1.y);
    a0[6] = (short)f2bf(xv1.z); a0[7] = (short)f2bf(xv1.w);
    a1[0] = (short)f2bf(xv2.x); a1[1] = (short)f2bf(xv2.y);
    a1[2] = (short)f2bf(xv2.z); a1[3] = (short)f2bf(xv2.w);
    a1[4] = (short)f2bf(xv3.x); a1[5] = (short)f2bf(xv3.y);
    a1[6] = (short)f2bf(xv3.z); a1[7] = (short)f2bf(xv3.w);

    const floatx4 zero = { 0.f, 0.f, 0.f, 0.f };

    // ---- Q and K ----
    const unsigned short* Wm[2] = { Wqt + h * 4096, Wkt + h * 4096 };
    const float* bm[2] = { bq + h * 64, bk + h * 64 };
    unsigned short* Om[2] = { Q, K };
    #pragma unroll
    for (int m = 0; m < 2; ++m) {
        const unsigned short* W = Wm[m];
        unsigned short* O = Om[m] + ((size_t)bh * 1024 + row0) * 64;
        #pragma unroll
        for (int t = 0; t < 4; ++t) {
            short8 b0 = *(const short8*)(W + (t * 16 + lrow) * 64 + quad * 8);
            short8 b1 = *(const short8*)(W + (t * 16 + lrow) * 64 + 32 + quad * 8);
            floatx4 acc = zero;
            acc = MFMA16(a0, b0, acc);
            acc = MFMA16(a1, b1, acc);
            float bias = bm[m][t * 16 + lrow];
            #pragma unroll
            for (int r = 0; r < 4; ++r) {
                float v = acc[r] + bias;
                if (m == 0) v *= scale;
                O[(quad * 4 + r) * 64 + t * 16 + lrow] = f2bf(v);
            }
        }
    }

    // ---- V transposed: D[e][seq] = sum_k Wv[k][e] * x[seq][k] ----
    {
        const unsigned short* W = Wvt + h * 4096;
        const float* bvh = bv + h * 64;
        unsigned short* O = Vt + (size_t)bh * 64 * 1024;
        #pragma unroll
        for (int t = 0; t < 4; ++t) {
            short8 wa0 = *(const short8*)(W + (t * 16 + lrow) * 64 + quad * 8);
            short8 wa1 = *(const short8*)(W + (t * 16 + lrow) * 64 + 32 + quad * 8);
            floatx4 acc = zero;
            acc = MFMA16(wa0, a0, acc);
            acc = MFMA16(wa1, a1, acc);
            #pragma unroll
            for (int r = 0; r < 4; ++r) {
                int e = t * 16 + quad * 4 + r;
                O[(size_t)e * 1024 + row0 + lrow] = f2bf(acc[r] + bvh[e]);
            }
        }
    }
}

// ---------------------------------------------------------------------------
// Phase 2: flash attention, register-only P. grid (16, 96), block 256.
// Wave = 32 q-rows x 512 kv (split-KV x2 across wave pairs, exact combine).
// Per 32-kv window: S^T via 2 permuted 16-row K tiles (kv = quad*8+r+4*tau),
// exp+trunc-pack in registers -> PV B-operand directly. No LDS in the loop.
// ---------------------------------------------------------------------------
__global__ __launch_bounds__(256) void attn_kernel(
    const unsigned short* __restrict__ Q, const unsigned short* __restrict__ K,
    const unsigned short* __restrict__ Vt, unsigned short* __restrict__ AO)
{
    __shared__ __align__(16) float smem[4352];  // obuf 4096 + pbuf 256 (17 KB)

    const int id = blockIdx.x + 16 * blockIdx.y;         // flat, x-fastest
    const int bh = (id & 7) * 12 + ((id % 96) >> 3);     // XCD-clustered bh
    const int qb = id / 96;                              // 0..15
    const int b = bh / 12, h = bh % 12;
    const int wave = threadIdx.x >> 6, lane = threadIdx.x & 63;
    const int lrow = lane & 15, quad = lane >> 4;
    const int mg = wave >> 1, half = wave & 1;
    const int qrow0 = qb * 64 + mg * 32;
    const int kv0 = half * 512;

    const unsigned short* Qb = Q + (size_t)bh * 65536;
    const unsigned short* Kb = K + (size_t)bh * 65536;
    const unsigned short* Vb = Vt + (size_t)bh * 65536;

    // Q fragments (B-operand of S^T: n=q=lane&15, k=quad*8+j over e)
    short8 aq[2][2];
    #pragma unroll
    for (int mm = 0; mm < 2; ++mm) {
        const unsigned short* qr = Qb + (size_t)(qrow0 + mm * 16 + lrow) * 64;
        aq[mm][0] = *(const short8*)(qr + quad * 8);
        aq[mm][1] = *(const short8*)(qr + 32 + quad * 8);
    }

    // permuted K row for S^T A-operand: kv_local(tile tau, m=lrow)
    //   = (lrow>>2)*8 + (lrow&3) + 4*tau
    const int krow_base = ((lrow >> 2) * 8) + (lrow & 3);

    const floatx4 zero = { 0.f, 0.f, 0.f, 0.f };
    float part[2] = { 0.f, 0.f };
    floatx4 Oacc[2][4];
    #pragma unroll
    for (int mm = 0; mm < 2; ++mm)
        #pragma unroll
        for (int t = 0; t < 4; ++t) Oacc[mm][t] = zero;

    #pragma unroll 2
    for (int jt = 0; jt < 16; ++jt) {
        const int j0 = kv0 + jt * 32;

        // K fragments for the two permuted 16-row tiles
        short8 kA[2][2];
        #pragma unroll
        for (int tau = 0; tau < 2; ++tau) {
            const unsigned short* kr =
                Kb + (size_t)(j0 + krow_base + 4 * tau) * 64;
            kA[tau][0] = *(const short8*)(kr + quad * 8);
            kA[tau][1] = *(const short8*)(kr + 32 + quad * 8);
        }
        // V^T fragments (A-operand of PV: m=e=lane&15, k=quad*8+j over kv)
        short8 vA[4];
        #pragma unroll
        for (int t = 0; t < 4; ++t)
            vA[t] = *(const short8*)(Vb + (size_t)(t * 16 + lrow) * 1024
                                     + j0 + quad * 8);

        #pragma unroll
        for (int mm = 0; mm < 2; ++mm) {
            // S^T tiles: D[kv][q], kv = quad*8 + r + 4*tau, q = lane&15
            floatx4 s0 = zero, s1 = zero;
            s0 = MFMA16(kA[0][0], aq[mm][0], s0);
            s0 = MFMA16(kA[0][1], aq[mm][1], s0);
            s1 = MFMA16(kA[1][0], aq[mm][0], s1);
            s1 = MFMA16(kA[1][1], aq[mm][1], s1);

            // p = 2^s; pack into PV B-operand (k = quad*8 + j, j=0..7)
            short8 pk;
            #pragma unroll
            for (int r = 0; r < 4; ++r) {
                float p0 = EXP2(s0[r]);
                float p1 = EXP2(s1[r]);
                part[mm] += p0 + p1;
                pk[r] = (short)f2bf_trunc(p0);
                pk[4 + r] = (short)f2bf_trunc(p1);
            }
            // O^T[e][q] accumulation
            #pragma unroll
            for (int t = 0; t < 4; ++t)
                Oacc[mm][t] = MFMA16(vA[t], pk, Oacc[mm][t]);
        }
    }

    // ---- combine KV halves (exact: O and sum(p) add linearly) ----
    float* obuf = smem;          // [mg][i=mm*16+t*4+r][lane] = 16 KB
    float* pbuf = smem + 4096;   // [mg][mm][lane] = 1 KB
    __syncthreads();
    if (half == 1) {
        #pragma unroll
        for (int mm = 0; mm < 2; ++mm) {
            #pragma unroll
            for (int t = 0; t < 4; ++t)
                #pragma unroll
                for (int r = 0; r < 4; ++r)
                    obuf[(mg * 32 + mm * 16 + t * 4 + r) * 64 + lane] = Oacc[mm][t][r];
            pbuf[(mg * 2 + mm) * 64 + lane] = part[mm];
        }
    }
    __syncthreads();
    if (half == 0) {
        #pragma unroll
        for (int mm = 0; mm < 2; ++mm) {
            float ts = part[mm] + pbuf[(mg * 2 + mm) * 64 + lane];
            ts += __shfl_xor(ts, 16);
            ts += __shfl_xor(ts, 32);
            float inv = RCP(ts);
            // q = lane&15 fixed per lane; e = t*16 + quad*4 + r consecutive
            unsigned short* orow = AO
                + ((size_t)(b * 1024 + qrow0 + mm * 16 + lrow)) * 768 + h * 64;
            #pragma unroll
            for (int t = 0; t < 4; ++t) {
                unsigned short pkd[4];
                #pragma unroll
                for (int r = 0; r < 4; ++r) {
                    float val = (Oacc[mm][t][r]
                        + obuf[(mg * 32 + mm * 16 + t * 4 + r) * 64 + lane]) * inv;
                    pkd[r] = f2bf(val);
                }
                *(uint2*)(orow + t * 16 + quad * 4) = *(uint2*)pkd;  // 8B store
            }
        }
    }
}

// ---------------------------------------------------------------------------
// Phase 3 (round-8 version): Y = AO @ Wo^T + bo. grid (12, 64), block 256;
// wave = 32 rows (B-frags reused across 2 m-tiles).
// ---------------------------------------------------------------------------
__global__ __launch_bounds__(256) void out_proj(
    const unsigned short* __restrict__ AO, const unsigned short* __restrict__ Wob,
    const float* __restrict__ bo, float* __restrict__ Y)
{
    const int wave = threadIdx.x >> 6, lane = threadIdx.x & 63;
    const int lrow = lane & 15, quad = lane >> 4;
    const int row0 = blockIdx.y * 128 + wave * 32;
    const int c0 = blockIdx.x * 64;

    const floatx4 zero = { 0.f, 0.f, 0.f, 0.f };
    floatx4 acc[2][4];
    #pragma unroll
    for (int m = 0; m < 2; ++m)
        #pragma unroll
        for (int t = 0; t < 4; ++t) acc[m][t] = zero;

    for (int k0 = 0; k0 < 768; k0 += 32) {
        short8 a[2];
        #pragma unroll
        for (int m = 0; m < 2; ++m)
            a[m] = *(const short8*)(AO + (size_t)(row0 + m * 16 + lrow) * 768
                                    + k0 + quad * 8);
        #pragma unroll
        for (int t = 0; t < 4; ++t) {
            short8 bfr = *(const short8*)(Wob + (size_t)(c0 + t * 16 + lrow) * 768
                                          + k0 + quad * 8);
            #pragma unroll
            for (int m = 0; m < 2; ++m)
                acc[m][t] = MFMA16(a[m], bfr, acc[m][t]);
        }
    }
    #pragma unroll
    for (int t = 0; t < 4; ++t) {
        float bias = bo[c0 + t * 16 + lrow];
        #pragma unroll
        for (int m = 0; m < 2; ++m)
            #pragma unroll
            for (int r = 0; r < 4; ++r) {
                Y[(size_t)(row0 + m * 16 + quad * 4 + r) * 768 + c0 + t * 16 + lrow]
                    = acc[m][t][r] + bias;
            }
    }
}

extern "C" void kernel_launch(void* const* d_in, const int* in_sizes, int n_in,
                              void* d_out, int out_size, void* d_ws, size_t ws_size,
                              hipStream_t stream)
{
    const float* x  = (const float*)d_in[0];
    const float* Wq = (const float*)d_in[1];
    const float* Wk = (const float*)d_in[2];
    const float* Wv = (const float*)d_in[3];
    const float* bq = (const float*)d_in[4];
    const float* bk = (const float*)d_in[5];
    const float* bv = (const float*)d_in[6];
    const float* Wo = (const float*)d_in[7];
    const float* bo = (const float*)d_in[8];

    // ws layout (bf16 elements)
    unsigned short* Q   = (unsigned short*)d_ws;        // 6291456
    unsigned short* K   = Q + 6291456;                  // 6291456
    unsigned short* Vt  = K + 6291456;                  // 6291456 (transposed)
    unsigned short* AO  = Vt + 6291456;                 // 6291456
    unsigned short* Wqt = AO + 6291456;                 // 49152
    unsigned short* Wkt = Wqt + 49152;                  // 49152
    unsigned short* Wvt = Wkt + 49152;                  // 49152
    unsigned short* Wob = Wvt + 49152;                  // 589824
    float* Y = (float*)d_out;

    prep_weights<<<dim3(576), 256, 0, stream>>>(Wq, Wk, Wv, Wo, Wqt, Wkt, Wvt, Wob);
    qkv_proj<<<dim3(16, 96), 256, 0, stream>>>(x, Wqt, Wkt, Wvt, bq, bk, bv, Q, K, Vt);
    attn_kernel<<<dim3(16, 96), 256, 0, stream>>>(Q, K, Vt, AO);
    out_proj<<<dim3(12, 64), 256, 0, stream>>>(AO, Wob, bo, Y);
}

// Round 12
// 172.106 us; speedup vs baseline: 1.5974x; 1.4882x over previous
//
#include <hip/hip_runtime.h>

// MHA: B=8, N=1024, D=768, H=12, HD=64. FLOAT32 in/out, bf16 MFMA internally.
// Round 12: canonical staged pattern (m93/m97) for attn + out_proj.
// attn: block = 64 q x one bh, full-KV sweep; per 64-kv tile K/Vt staged
//       cooperatively into padded LDS (coalesced), fragments via ds_read_b128;
//       register-only S^T/PV transform kept (P never touches LDS).
// out_proj: staged 128x64 GEMM tile, BK=32, wave = 64x32.

typedef __attribute__((ext_vector_type(8))) short short8;   // 8 x bf16 bits
typedef __attribute__((ext_vector_type(4))) float floatx4;  // MFMA acc

#define MFMA16(a, b, c) __builtin_amdgcn_mfma_f32_16x16x32_bf16((a), (b), (c), 0, 0, 0)

#if __has_builtin(__builtin_amdgcn_exp2f)
#define EXP2(x) __builtin_amdgcn_exp2f(x)
#else
#define EXP2(x) __expf(0.6931471805599453f * (x))
#endif
#if __has_builtin(__builtin_amdgcn_rcpf)
#define RCP(x) __builtin_amdgcn_rcpf(x)
#else
#define RCP(x) (1.0f / (x))
#endif

__device__ __forceinline__ unsigned short f2bf(float f) {
    union { float f; unsigned int i; } c;
    c.f = f;
    unsigned int i = c.i;
    return (unsigned short)((i + 0x7fffu + ((i >> 16) & 1u)) >> 16);  // RNE
}
__device__ __forceinline__ unsigned short f2bf_trunc(float f) {
    union { float f; unsigned int i; } c;
    c.f = f;
    return (unsigned short)(c.i >> 16);
}

// ---------------------------------------------------------------------------
// Phase 0: Wt[h][e][k] = W[h][k][e] (bf16), Wo_bf = bf16(Wo).
// ---------------------------------------------------------------------------
__global__ __launch_bounds__(256) void prep_weights(
    const float* __restrict__ Wq, const float* __restrict__ Wk,
    const float* __restrict__ Wv, const float* __restrict__ Wo,
    unsigned short* __restrict__ Wqt, unsigned short* __restrict__ Wkt,
    unsigned short* __restrict__ Wvt, unsigned short* __restrict__ Wob)
{
    int tid = blockIdx.x * 256 + threadIdx.x;  // 0..147455
    if (tid < 49152) {                          // 12 heads * 4096 only
        int h = tid >> 12, r = tid & 4095;
        int e = r >> 6, k = r & 63;
        int src = h * 4096 + k * 64 + e, dst = h * 4096 + e * 64 + k;
        Wqt[dst] = f2bf(Wq[src]);
        Wkt[dst] = f2bf(Wk[src]);
        Wvt[dst] = f2bf(Wv[src]);
    }
    for (int i = tid; i < 589824; i += 147456) Wob[i] = f2bf(Wo[i]);
}

// ---------------------------------------------------------------------------
// Phase 1 (round-8 version): Q/K (Q pre-scaled by 768^-0.5*log2e), Vt.
// grid (16, 96), block 256 (4 waves x 16 rows). float4 x-loads.
// ---------------------------------------------------------------------------
__global__ __launch_bounds__(256) void qkv_proj(
    const float* __restrict__ x,
    const unsigned short* __restrict__ Wqt, const unsigned short* __restrict__ Wkt,
    const unsigned short* __restrict__ Wvt,
    const float* __restrict__ bq, const float* __restrict__ bk,
    const float* __restrict__ bv,
    unsigned short* __restrict__ Q, unsigned short* __restrict__ K,
    unsigned short* __restrict__ Vt)
{
    const int bh = blockIdx.y;
    const int b = bh / 12, h = bh % 12;
    const int wave = threadIdx.x >> 6, lane = threadIdx.x & 63;
    const int lrow = lane & 15, quad = lane >> 4;
    const int row0 = blockIdx.x * 64 + wave * 16;
    const float scale = 0.052058776672f;  // 768^-0.5 * log2(e): p = 2^s

    const float* xrow = x + ((size_t)(b * 1024 + row0 + lrow)) * 768 + h * 64;
    float4 xv0 = *(const float4*)(xrow + quad * 8);
    float4 xv1 = *(const float4*)(xrow + quad * 8 + 4);
    float4 xv2 = *(const float4*)(xrow + 32 + quad * 8);
    float4 xv3 = *(const float4*)(xrow + 32 + quad * 8 + 4);
    short8 a0, a1;
    a0[0] = (short)f2bf(xv0.x); a0[1] = (short)f2bf(xv0.y);
    a0[2] = (short)f2bf(xv0.z); a0[3] = (short)f2bf(xv0.w);
    a0[4] = (short)f2bf(xv1.x); a0[5] = (short)f2bf(xv1.y);
    a0[6] = (short)f2bf(xv1.z); a0[7] = (short)f2bf(xv1.w);
    a1[0] = (short)f2bf(xv2.x); a1[1] = (short)f2bf(xv2.y);
    a1[2] = (short)f2bf(xv2.z); a1[3] = (short)f2bf(xv2.w);
    a1[4] = (short)f2bf(xv3.x); a1[5] = (short)f2bf(xv3.y);
    a1[6] = (short)f2bf(xv3.z); a1[7] = (short)f2bf(xv3.w);

    const floatx4 zero = { 0.f, 0.f, 0.f, 0.f };

    // ---- Q and K ----
    const unsigned short* Wm[2] = { Wqt + h * 4096, Wkt + h * 4096 };
    const float* bm[2] = { bq + h * 64, bk + h * 64 };
    unsigned short* Om[2] = { Q, K };
    #pragma unroll
    for (int m = 0; m < 2; ++m) {
        const unsigned short* W = Wm[m];
        unsigned short* O = Om[m] + ((size_t)bh * 1024 + row0) * 64;
        #pragma unroll
        for (int t = 0; t < 4; ++t) {
            short8 b0 = *(const short8*)(W + (t * 16 + lrow) * 64 + quad * 8);
            short8 b1 = *(const short8*)(W + (t * 16 + lrow) * 64 + 32 + quad * 8);
            floatx4 acc = zero;
            acc = MFMA16(a0, b0, acc);
            acc = MFMA16(a1, b1, acc);
            float bias = bm[m][t * 16 + lrow];
            #pragma unroll
            for (int r = 0; r < 4; ++r) {
                float v = acc[r] + bias;
                if (m == 0) v *= scale;
                O[(quad * 4 + r) * 64 + t * 16 + lrow] = f2bf(v);
            }
        }
    }

    // ---- V transposed: D[e][seq] = sum_k Wv[k][e] * x[seq][k] ----
    {
        const unsigned short* W = Wvt + h * 4096;
        const float* bvh = bv + h * 64;
        unsigned short* O = Vt + (size_t)bh * 64 * 1024;
        #pragma unroll
        for (int t = 0; t < 4; ++t) {
            short8 wa0 = *(const short8*)(W + (t * 16 + lrow) * 64 + quad * 8);
            short8 wa1 = *(const short8*)(W + (t * 16 + lrow) * 64 + 32 + quad * 8);
            floatx4 acc = zero;
            acc = MFMA16(wa0, a0, acc);
            acc = MFMA16(wa1, a1, acc);
            #pragma unroll
            for (int r = 0; r < 4; ++r) {
                int e = t * 16 + quad * 4 + r;
                O[(size_t)e * 1024 + row0 + lrow] = f2bf(acc[r] + bvh[e]);
            }
        }
    }
}

// ---------------------------------------------------------------------------
// Phase 2: flash attention, staged K/V + register-only P. grid (16, 96),
// block 256 = 4 waves x 16 q-rows, full 1024-KV sweep in 16 tiles of 64.
// Per tile: cooperative coalesced staging of K[64][64] and Vt[64][64] into
// padded LDS (stride 72 u16: K-frag reads 4-way-conflict, V-frag 2-way);
// then S^T via permuted K rows (kv = quad*8+r+4*tau) -> exp -> in-register
// pack -> PV. No split-KV, no combine, no P in LDS.
// ---------------------------------------------------------------------------
__global__ __launch_bounds__(256) void attn_kernel(
    const unsigned short* __restrict__ Q, const unsigned short* __restrict__ K,
    const unsigned short* __restrict__ Vt, unsigned short* __restrict__ AO)
{
    __shared__ __align__(16) unsigned short Klds[64 * 72];  // 9216 B
    __shared__ __align__(16) unsigned short Vlds[64 * 72];  // 9216 B

    const int id = blockIdx.x + 16 * blockIdx.y;         // flat, x-fastest
    const int bh = (id & 7) * 12 + ((id % 96) >> 3);     // XCD-clustered bh
    const int qb = id / 96;                              // 0..15
    const int b = bh / 12, h = bh % 12;
    const int wave = threadIdx.x >> 6, lane = threadIdx.x & 63;
    const int lrow = lane & 15, quad = lane >> 4;
    const int qrow0 = qb * 64 + wave * 16;

    const unsigned short* Qb = Q + (size_t)bh * 65536;
    const unsigned short* Kb = K + (size_t)bh * 65536;
    const unsigned short* Vb = Vt + (size_t)bh * 65536;

    // staging coordinates: 8 chunks of 8 u16 per 64-elem row, 32 rows/round
    const int tch = threadIdx.x & 7, trow = threadIdx.x >> 3;

    // Q fragments (B-operand of S^T: n=q=lane&15, k=quad*8+j over e)
    short8 aq0, aq1;
    {
        const unsigned short* qr = Qb + (size_t)(qrow0 + lrow) * 64;
        aq0 = *(const short8*)(qr + quad * 8);
        aq1 = *(const short8*)(qr + 32 + quad * 8);
    }

    // permuted K row for S^T A-operand: kv_local(tau) = (lrow>>2)*8+(lrow&3)+4tau
    const int krow_base = ((lrow >> 2) * 8) + (lrow & 3);

    const floatx4 zero = { 0.f, 0.f, 0.f, 0.f };
    float part = 0.f;
    floatx4 Oacc[4];
    #pragma unroll
    for (int t = 0; t < 4; ++t) Oacc[t] = zero;

    for (int jt = 0; jt < 16; ++jt) {
        const int j0 = jt * 64;

        // ---- cooperative staging (coalesced b128 global -> padded LDS) ----
        #pragma unroll
        for (int rr = 0; rr < 2; ++rr) {
            int r = trow + rr * 32;
            *(short8*)&Klds[r * 72 + tch * 8] =
                *(const short8*)(Kb + (size_t)(j0 + r) * 64 + tch * 8);
            *(short8*)&Vlds[r * 72 + tch * 8] =
                *(const short8*)(Vb + (size_t)r * 1024 + j0 + tch * 8);
        }
        __syncthreads();

        // ---- two 32-kv windows per tile ----
        #pragma unroll
        for (int w = 0; w < 2; ++w) {
            // K fragments for the two permuted 16-row tiles
            short8 kA[2][2];
            #pragma unroll
            for (int tau = 0; tau < 2; ++tau) {
                int kr = w * 32 + krow_base + 4 * tau;
                kA[tau][0] = *(const short8*)&Klds[kr * 72 + quad * 8];
                kA[tau][1] = *(const short8*)&Klds[kr * 72 + 32 + quad * 8];
            }
            // V^T fragments (A-operand of PV: m=e=lane&15, k=quad*8+j over kv)
            short8 vA[4];
            #pragma unroll
            for (int t = 0; t < 4; ++t)
                vA[t] = *(const short8*)&Vlds[(t * 16 + lrow) * 72
                                              + w * 32 + quad * 8];

            // S^T tiles: D[kv][q], kv = quad*8 + r + 4*tau, q = lane&15
            floatx4 s0 = zero, s1 = zero;
            s0 = MFMA16(kA[0][0], aq0, s0);
            s0 = MFMA16(kA[0][1], aq1, s0);
            s1 = MFMA16(kA[1][0], aq0, s1);
            s1 = MFMA16(kA[1][1], aq1, s1);

            // p = 2^s; pack into PV B-operand (k = quad*8 + j)
            short8 pk;
            #pragma unroll
            for (int r = 0; r < 4; ++r) {
                float p0 = EXP2(s0[r]);
                float p1 = EXP2(s1[r]);
                part += p0 + p1;
                pk[r] = (short)f2bf_trunc(p0);
                pk[4 + r] = (short)f2bf_trunc(p1);
            }
            // O^T[e][q] accumulation
            #pragma unroll
            for (int t = 0; t < 4; ++t)
                Oacc[t] = MFMA16(vA[t], pk, Oacc[t]);
        }
        __syncthreads();
    }

    // ---- epilogue: per-lane row sum across the 4 quads holding q=lane&15 ----
    float ts = part;
    ts += __shfl_xor(ts, 16);
    ts += __shfl_xor(ts, 32);
    float inv = RCP(ts);
    unsigned short* orow = AO
        + ((size_t)(b * 1024 + qrow0 + lrow)) * 768 + h * 64;
    #pragma unroll
    for (int t = 0; t < 4; ++t) {
        unsigned short pkd[4];
        #pragma unroll
        for (int r = 0; r < 4; ++r)
            pkd[r] = f2bf(Oacc[t][r] * inv);
        *(uint2*)(orow + t * 16 + quad * 4) = *(uint2*)pkd;  // 8B packed store
    }
}

// ---------------------------------------------------------------------------
// Phase 3: staged GEMM. Y = AO @ Wo^T + bo. Tile 128x64, BK=32, 24 k-iters.
// grid (64, 12) (x-fastest -> XCD = rowblk%8, AO row-tile L2-pinned).
// Block 256 = 2x2 waves of 64x32. A/B tiles in padded LDS (stride 40 u16).
// ---------------------------------------------------------------------------
__global__ __launch_bounds__(256) void out_proj(
    const unsigned short* __restrict__ AO, const unsigned short* __restrict__ Wob,
    const float* __restrict__ bo, float* __restrict__ Y)
{
    __shared__ __align__(16) unsigned short Alds[128 * 40];  // 10240 B
    __shared__ __align__(16) unsigned short Blds[64 * 40];   //  5120 B

    const int wave = threadIdx.x >> 6, lane = threadIdx.x & 63;
    const int lrow = lane & 15, quad = lane >> 4;
    const int row0 = blockIdx.x * 128;
    const int c0 = blockIdx.y * 64;
    const int wrow = (wave >> 1) * 64, wcol = (wave & 1) * 32;

    // staging coords: 4 chunks of 8 u16 per 32-elem row
    const int tch = threadIdx.x & 3, trow = threadIdx.x >> 2;  // 64 rows/round

    const floatx4 zero = { 0.f, 0.f, 0.f, 0.f };
    floatx4 acc[4][2];
    #pragma unroll
    for (int t = 0; t < 4; ++t)
        #pragma unroll
        for (int u = 0; u < 2; ++u) acc[t][u] = zero;

    for (int k0 = 0; k0 < 768; k0 += 32) {
        // ---- stage A (128x32) and B (64x32), coalesced ----
        #pragma unroll
        for (int rr = 0; rr < 2; ++rr) {
            int r = trow + rr * 64;
            *(short8*)&Alds[r * 40 + tch * 8] =
                *(const short8*)(AO + (size_t)(row0 + r) * 768 + k0 + tch * 8);
        }
        *(short8*)&Blds[trow * 40 + tch * 8] =
            *(const short8*)(Wob + (size_t)(c0 + trow) * 768 + k0 + tch * 8);
        __syncthreads();

        // ---- fragments + MFMA ----
        short8 aF[4], bF[2];
        #pragma unroll
        for (int t = 0; t < 4; ++t)
            aF[t] = *(const short8*)&Alds[(wrow + t * 16 + lrow) * 40 + quad * 8];
        #pragma unroll
        for (int u = 0; u < 2; ++u)
            bF[u] = *(const short8*)&Blds[(wcol + u * 16 + lrow) * 40 + quad * 8];

        #pragma unroll
        for (int t = 0; t < 4; ++t)
            #pragma unroll
            for (int u = 0; u < 2; ++u)
                acc[t][u] = MFMA16(aF[t], bF[u], acc[t][u]);
        __syncthreads();
    }

    #pragma unroll
    for (int u = 0; u < 2; ++u) {
        float bias = bo[c0 + wcol + u * 16 + lrow];
        #pragma unroll
        for (int t = 0; t < 4; ++t)
            #pragma unroll
            for (int r = 0; r < 4; ++r) {
                Y[(size_t)(row0 + wrow + t * 16 + quad * 4 + r) * 768
                  + c0 + wcol + u * 16 + lrow] = acc[t][u][r] + bias;
            }
    }
}

extern "C" void kernel_launch(void* const* d_in, const int* in_sizes, int n_in,
                              void* d_out, int out_size, void* d_ws, size_t ws_size,
                              hipStream_t stream)
{
    const float* x  = (const float*)d_in[0];
    const float* Wq = (const float*)d_in[1];
    const float* Wk = (const float*)d_in[2];
    const float* Wv = (const float*)d_in[3];
    const float* bq = (const float*)d_in[4];
    const float* bk = (const float*)d_in[5];
    const float* bv = (const float*)d_in[6];
    const float* Wo = (const float*)d_in[7];
    const float* bo = (const float*)d_in[8];

    // ws layout (bf16 elements)
    unsigned short* Q   = (unsigned short*)d_ws;        // 6291456
    unsigned short* K   = Q + 6291456;                  // 6291456
    unsigned short* Vt  = K + 6291456;                  // 6291456 (transposed)
    unsigned short* AO  = Vt + 6291456;                 // 6291456
    unsigned short* Wqt = AO + 6291456;                 // 49152
    unsigned short* Wkt = Wqt + 49152;                  // 49152
    unsigned short* Wvt = Wkt + 49152;                  // 49152
    unsigned short* Wob = Wvt + 49152;                  // 589824
    float* Y = (float*)d_out;

    prep_weights<<<dim3(576), 256, 0, stream>>>(Wq, Wk, Wv, Wo, Wqt, Wkt, Wvt, Wob);
    qkv_proj<<<dim3(16, 96), 256, 0, stream>>>(x, Wqt, Wkt, Wvt, bq, bk, bv, Q, K, Vt);
    attn_kernel<<<dim3(16, 96), 256, 0, stream>>>(Q, K, Vt, AO);
    out_proj<<<dim3(64, 12), 256, 0, stream>>>(AO, Wob, bo, Y);
}